// Round 6
// baseline (412.742 us; speedup 1.0000x reference)
//
#include <hip/hip_runtime.h>

typedef __bf16 bf16_t;
typedef bf16_t bf16x8 __attribute__((ext_vector_type(8)));
typedef float f32x4v __attribute__((ext_vector_type(4)));
typedef unsigned int u32;

__device__ __forceinline__ void gload16(const bf16_t* g, bf16_t* l) {
    __builtin_amdgcn_global_load_lds((const __attribute__((address_space(1))) u32*)g,
                                     (__attribute__((address_space(3))) u32*)l, 16, 0, 0);
}

// ---------------------------------------------------------------- pack f32 -> bf16 (segmented)
struct PackBDesc {
    int nseg;
    int blkOf[21];
    const float* src[20];
    bf16_t* dst[20];
    int chunks[20];
    int dstLd[20];
    int shift[20];
};

__global__ __launch_bounds__(256) void packb_k(PackBDesc d) {
    int b = blockIdx.x;
    int s = 0;
    while (s + 1 < d.nseg && b >= d.blkOf[s + 1]) ++s;
    int idx = (b - d.blkOf[s]) * 256 + threadIdx.x;
    if (idx >= d.chunks[s]) return;
    const float* src = d.src[s] + (size_t)idx * 8;
    int r = idx >> d.shift[s];
    int c8 = idx & ((1 << d.shift[s]) - 1);
    bf16_t* dst = d.dst[s] + (size_t)r * d.dstLd[s] + (size_t)c8 * 8;
    float4 v0 = reinterpret_cast<const float4*>(src)[0];
    float4 v1 = reinterpret_cast<const float4*>(src)[1];
    bf16x8 o;
    o[0] = (bf16_t)v0.x; o[1] = (bf16_t)v0.y; o[2] = (bf16_t)v0.z; o[3] = (bf16_t)v0.w;
    o[4] = (bf16_t)v1.x; o[5] = (bf16_t)v1.y; o[6] = (bf16_t)v1.z; o[7] = (bf16_t)v1.w;
    *reinterpret_cast<bf16x8*>(dst) = o;
}

// ---------------------------------------------------------------- pack f32 -> f32 (linear copies)
struct PackFDesc {
    int nseg;
    int blkOf[15];
    const float* src[14];
    float* dst[14];
    int n[14];
};

__global__ __launch_bounds__(256) void packf_k(PackFDesc d) {
    int b = blockIdx.x;
    int s = 0;
    while (s + 1 < d.nseg && b >= d.blkOf[s + 1]) ++s;
    int idx = (b - d.blkOf[s]) * 256 + threadIdx.x;
    if (idx >= d.n[s]) return;
    d.dst[s][idx] = d.src[s][idx];
}

// ---------------------------------------------------------------- GEMM, double-buffered 2-phase
// C[M=4096, N] = A @ B^T (+bias). A: [tokens][lda] via row remap; B: [N][lda] bf16, K window
// [kStart, kStart+kLen). BM=128, BK=32, 256 threads (4 waves 2x2), BN in {128, 64}.
// EPI: 0 = bf16 store, 1 = gelu->bf16, 3 = f32 store, 4 = f32 (+ gate*obcat mix when obcat)
template <int EPI, int BN>
__global__ __launch_bounds__(256) void gemm3(
    const bf16_t* __restrict__ A, int aBS, int aRowOff, int lda,
    const bf16_t* __restrict__ B,
    const float* __restrict__ bias,
    void* __restrict__ Out, int ldo,
    const float* __restrict__ gate, const float* __restrict__ obcat,
    int kStart, int kLen) {
    constexpr int NB = BN / 32;
    constexpr int WN = BN / 2;
    __shared__ __attribute__((aligned(16))) bf16_t As[2][128 * 32];
    __shared__ __attribute__((aligned(16))) bf16_t Bs[2][BN * 32];
    const int tid = threadIdx.x, lane = tid & 63, w = tid >> 6;
    const int wm = w >> 1, wn = w & 1;
    const int l15 = lane & 15, l16 = lane >> 4;
    const int tm = blockIdx.y, tn = blockIdx.x;

    auto remap = [&](int m) { return (m >> 10) * aBS + aRowOff + (m & 1023); };

    // staging geometry: per K-tile, 16-row x 32-col chunks; lane -> (row lane>>2, col (lane&3)*8)
    const int colA = (lane & 3) * 8;
    const int rA0 = 32 * w + (lane >> 2);
    const int rA1 = rA0 + 16;
    const bf16_t* aSrc0 = A + (size_t)remap(tm * 128 + rA0) * lda + kStart + colA;
    const bf16_t* aSrc1 = A + (size_t)remap(tm * 128 + rA1) * lda + kStart + colA;
    const bf16_t *bSrc0, *bSrc1 = nullptr;
    if constexpr (BN == 128) {
        bSrc0 = B + (size_t)(tn * 128 + rA0) * lda + kStart + colA;
        bSrc1 = B + (size_t)(tn * 128 + rA1) * lda + kStart + colA;
    } else {
        bSrc0 = B + (size_t)(tn * 64 + 16 * w + (lane >> 2)) * lda + kStart + colA;
    }

    auto stage = [&](int buf, int t) {
        const size_t o = (size_t)t * 32;
        gload16(aSrc0 + o, &As[buf][(2 * w) * 512]);
        gload16(aSrc1 + o, &As[buf][(2 * w + 1) * 512]);
        if constexpr (BN == 128) {
            gload16(bSrc0 + o, &Bs[buf][(2 * w) * 512]);
            gload16(bSrc1 + o, &Bs[buf][(2 * w + 1) * 512]);
        } else {
            gload16(bSrc0 + o, &Bs[buf][w * 512]);
        }
    };

    f32x4v acc[4][NB] = {};
    const int nt = kLen / 32;

    stage(0, 0);
    __syncthreads();
    int cur = 0;
    for (int t = 0; t < nt; ++t) {
        if (t + 1 < nt) stage(cur ^ 1, t + 1);   // issue next-tile loads early
        bf16x8 af[4], bff[NB];
#pragma unroll
        for (int mi = 0; mi < 4; ++mi)
            af[mi] = *reinterpret_cast<const bf16x8*>(&As[cur][(wm * 64 + mi * 16 + l15) * 32 + l16 * 8]);
#pragma unroll
        for (int ni = 0; ni < NB; ++ni)
            bff[ni] = *reinterpret_cast<const bf16x8*>(&Bs[cur][(wn * WN + ni * 16 + l15) * 32 + l16 * 8]);
#pragma unroll
        for (int mi = 0; mi < 4; ++mi)
#pragma unroll
            for (int ni = 0; ni < NB; ++ni)
                acc[mi][ni] = __builtin_amdgcn_mfma_f32_16x16x32_bf16(af[mi], bff[ni], acc[mi][ni], 0, 0, 0);
        __syncthreads();   // drains this iteration's stage (vmcnt0) + guards buffer reuse
        cur ^= 1;
    }

#pragma unroll
    for (int mi = 0; mi < 4; ++mi) {
#pragma unroll
        for (int ni = 0; ni < NB; ++ni) {
#pragma unroll
            for (int i = 0; i < 4; ++i) {
                int row = tm * 128 + wm * 64 + mi * 16 + l16 * 4 + i;
                int n = tn * BN + wn * WN + ni * 16 + l15;
                float v = acc[mi][ni][i];
                if (bias) v += bias[n];
                if constexpr (EPI == 0) {
                    ((bf16_t*)Out)[(size_t)row * ldo + n] = (bf16_t)v;
                } else if constexpr (EPI == 1) {
                    float g = 0.5f * v * (1.0f + erff(v * 0.70710678118654752f));
                    ((bf16_t*)Out)[(size_t)row * ldo + n] = (bf16_t)g;
                } else if constexpr (EPI == 3) {
                    ((float*)Out)[(size_t)row * ldo + n] = v;
                } else {
                    if (obcat) {
#pragma unroll
                        for (int p = 0; p < 5; ++p) {
                            float c = (p == 0) ? 2.0f : 1.0f;  // mca's ob appears twice
                            v += gate[row * 5 + p] * c * obcat[p * 512 + n];
                        }
                    }
                    ((float*)Out)[(size_t)row * ldo + n] = v;
                }
            }
        }
    }
}

// ---------------------------------------------------------------- attention
// Q/K/V separate pointers+strides (head-major 64 cols each).
// MASK: 0 none, 1 rev (banded, direct), 2 fwd. SPLITK: 0 direct gated write; 1 gated partials.
template <int MASK, int SPLITK>
__global__ __launch_bounds__(256) void attn3_k(
    const bf16_t* __restrict__ Q, int ldq,
    const bf16_t* __restrict__ Kp, int ldk,
    const bf16_t* __restrict__ Vp, int ldv,
    bf16_t* __restrict__ outCat, int segOff,
    bf16_t* __restrict__ Op, float* __restrict__ Mp, float* __restrict__ Lp,
    const float* __restrict__ gate, int gidx) {
    __shared__ __attribute__((aligned(16))) bf16_t Ks[32][72];
    __shared__ __attribute__((aligned(16))) bf16_t Vt[64][40];
    __shared__ __attribute__((aligned(16))) bf16_t Ps[4][16][40];

    const int tid = threadIdx.x;
    const int lane = tid & 63;
    const int w = tid >> 6;
    const int l15 = lane & 15, l16 = lane >> 4;
    const int qt = blockIdx.x, h = blockIdx.y, z = blockIdx.z;
    int b, split;
    if (SPLITK) { b = z & 3; split = z >> 2; } else { b = z; split = 0; }

    const int qr = qt * 64 + w * 16;
    const int qrow = b * 1024 + qr;
    const int qblk = qr >> 5;
    const int qg = ((w & 1) * 16) + l15;

    bf16x8 aq[2];
#pragma unroll
    for (int s = 0; s < 2; ++s)
        aq[s] = *reinterpret_cast<const bf16x8*>(
            Q + (size_t)(qrow + l15) * ldq + h * 64 + s * 32 + l16 * 8);

    float mrow = -1e30f, lsum = 0.f;
    f32x4v accO[4] = {};

    const int srow = tid >> 3, scol8 = (tid & 7) * 8;
    const bf16_t* kbase = Kp + (size_t)(b * 1024) * ldk + h * 64 + scol8;
    const bf16_t* vbase = Vp + (size_t)(b * 1024) * ldv + h * 64 + scol8;

    int kt0, ktEnd;
    if (SPLITK) { kt0 = split * 16; ktEnd = kt0 + 16; }
    else {
        int qb0 = qt * 2;
        kt0 = qb0 - 3; if (kt0 < 0) kt0 = 0;
        ktEnd = qb0 + 5; if (ktEnd > 32) ktEnd = 32;
    }

    bf16x8 rk, rv, rk2, rv2;
    rk = *reinterpret_cast<const bf16x8*>(kbase + (size_t)(kt0 * 32 + srow) * ldk);
    rv = *reinterpret_cast<const bf16x8*>(vbase + (size_t)(kt0 * 32 + srow) * ldv);

    for (int kt = kt0; kt < ktEnd; ++kt) {
        __syncthreads();
        *reinterpret_cast<bf16x8*>(&Ks[srow][scol8]) = rk;
#pragma unroll
        for (int j = 0; j < 8; ++j) {
            int d = scol8 + j;
            Vt[d][srow ^ (((d >> 3) & 3) << 3)] = rv[j];
        }
        if (kt + 1 < ktEnd) {
            rk2 = *reinterpret_cast<const bf16x8*>(kbase + (size_t)((kt + 1) * 32 + srow) * ldk);
            rv2 = *reinterpret_cast<const bf16x8*>(vbase + (size_t)((kt + 1) * 32 + srow) * ldv);
        }
        __syncthreads();

        int bd = qblk - kt; if (bd < 0) bd = -bd;
        const bool active = (MASK != 1) || (bd <= 3);
        if (active) {
            bf16x8 k00 = *reinterpret_cast<const bf16x8*>(&Ks[l15][l16 * 8]);
            bf16x8 k01 = *reinterpret_cast<const bf16x8*>(&Ks[l15][32 + l16 * 8]);
            bf16x8 k10 = *reinterpret_cast<const bf16x8*>(&Ks[16 + l15][l16 * 8]);
            bf16x8 k11 = *reinterpret_cast<const bf16x8*>(&Ks[16 + l15][32 + l16 * 8]);
            f32x4v z0 = {}, z1 = {};
            z0 = __builtin_amdgcn_mfma_f32_16x16x32_bf16(k00, aq[0], z0, 0, 0, 0);
            z0 = __builtin_amdgcn_mfma_f32_16x16x32_bf16(k01, aq[1], z0, 0, 0, 0);
            z1 = __builtin_amdgcn_mfma_f32_16x16x32_bf16(k10, aq[0], z1, 0, 0, 0);
            z1 = __builtin_amdgcn_mfma_f32_16x16x32_bf16(k11, aq[1], z1, 0, 0, 0);

            const bool needMask = (MASK == 1) || (MASK == 2 && bd <= 3);
            float p[2][4];
#pragma unroll
            for (int n = 0; n < 2; ++n) {
                f32x4v sv = n ? z1 : z0;
#pragma unroll
                for (int i = 0; i < 4; ++i) {
                    float v = sv[i] * 0.125f;
                    if (needMask) {
                        int k5 = n * 16 + l16 * 4 + i;
                        int dq = qg - k5; if (dq < 0) dq = -dq;
                        bool inside = (dq <= 3);
                        if (MASK == 1 ? !inside : inside) v = -1e30f;
                    }
                    p[n][i] = v;
                }
            }
            float tmx = p[0][0];
            tmx = fmaxf(tmx, p[0][1]); tmx = fmaxf(tmx, p[0][2]); tmx = fmaxf(tmx, p[0][3]);
            tmx = fmaxf(tmx, p[1][0]); tmx = fmaxf(tmx, p[1][1]);
            tmx = fmaxf(tmx, p[1][2]); tmx = fmaxf(tmx, p[1][3]);
            tmx = fmaxf(tmx, __shfl_xor(tmx, 16, 64));
            tmx = fmaxf(tmx, __shfl_xor(tmx, 32, 64));
            float mn = fmaxf(mrow, tmx);
            float fac = __expf(mrow - mn);
            mrow = mn;
            float rs = 0.f;
#pragma unroll
            for (int n = 0; n < 2; ++n)
#pragma unroll
                for (int i = 0; i < 4; ++i) {
                    p[n][i] = __expf(p[n][i] - mn);
                    rs += p[n][i];
                }
            rs += __shfl_xor(rs, 16, 64);
            rs += __shfl_xor(rs, 32, 64);
            lsum = lsum * fac + rs;

            float facq[4];
#pragma unroll
            for (int i = 0; i < 4; ++i) facq[i] = __shfl(fac, l16 * 4 + i, 64);
#pragma unroll
            for (int dblk = 0; dblk < 4; ++dblk)
#pragma unroll
                for (int i = 0; i < 4; ++i) accO[dblk][i] *= facq[i];

#pragma unroll
            for (int n = 0; n < 2; ++n)
#pragma unroll
                for (int i = 0; i < 4; ++i)
                    Ps[w][l15][n * 16 + l16 * 4 + i] = (bf16_t)p[n][i];
            bf16x8 pa = *reinterpret_cast<const bf16x8*>(&Ps[w][l15][l16 * 8]);

#pragma unroll
            for (int dblk = 0; dblk < 4; ++dblk) {
                int d = dblk * 16 + l15;
                bf16x8 bv = *reinterpret_cast<const bf16x8*>(&Vt[d][(l16 ^ ((d >> 3) & 3)) * 8]);
                accO[dblk] = __builtin_amdgcn_mfma_f32_16x16x32_bf16(pa, bv, accO[dblk], 0, 0, 0);
            }
        }
        rk = rk2; rv = rv2;
    }

    if (SPLITK == 0) {
        float inv = 1.0f / lsum;
        float invq[4];
#pragma unroll
        for (int i = 0; i < 4; ++i) invq[i] = __shfl(inv, l16 * 4 + i, 64);
#pragma unroll
        for (int dblk = 0; dblk < 4; ++dblk)
#pragma unroll
            for (int i = 0; i < 4; ++i) {
                float g = gate[(size_t)(qrow + l16 * 4 + i) * 5 + gidx];
                outCat[(size_t)(qrow + l16 * 4 + i) * 3072 + segOff + h * 64 + dblk * 16 + l15] =
                    (bf16_t)(accO[dblk][i] * invq[i] * g);
            }
    } else {
        int pb = ((split * 4 + b) * 8 + h) * 1024 + qr;
        if (l16 == 0) { Mp[pb + l15] = mrow; Lp[pb + l15] = lsum; }
#pragma unroll
        for (int dblk = 0; dblk < 4; ++dblk)
#pragma unroll
            for (int i = 0; i < 4; ++i) {
                float g = gate[(size_t)(qrow + l16 * 4 + i) * 5 + gidx];
                Op[(size_t)(pb + l16 * 4 + i) * 64 + dblk * 16 + l15] = (bf16_t)(accO[dblk][i] * g);
            }
    }
}

// ---------------------------------------------------------------- split-K merge
__global__ __launch_bounds__(256) void merge_k(const bf16_t* __restrict__ Op,
                                               const float* __restrict__ Mp,
                                               const float* __restrict__ Lp,
                                               bf16_t* __restrict__ outCat, int segOff) {
    int idx = blockIdx.x * 256 + threadIdx.x;
    int dg = idx & 7;
    int q = (idx >> 3) & 1023;
    int h = (idx >> 13) & 7;
    int b = idx >> 16;
    int r0 = ((0 * 4 + b) * 8 + h) * 1024 + q;
    int r1 = ((1 * 4 + b) * 8 + h) * 1024 + q;
    float m0 = Mp[r0], m1 = Mp[r1], l0 = Lp[r0], l1 = Lp[r1];
    float M = fmaxf(m0, m1);
    float w0 = __expf(m0 - M), w1 = __expf(m1 - M);
    float den = 1.0f / (l0 * w0 + l1 * w1);
    bf16x8 o0 = *reinterpret_cast<const bf16x8*>(Op + (size_t)r0 * 64 + dg * 8);
    bf16x8 o1 = *reinterpret_cast<const bf16x8*>(Op + (size_t)r1 * 64 + dg * 8);
    bf16x8 o;
#pragma unroll
    for (int j = 0; j < 8; ++j)
        o[j] = (bf16_t)(((float)o0[j] * w0 + (float)o1[j] * w1) * den);
    *reinterpret_cast<bf16x8*>(outCat + (size_t)(b * 1024 + q) * 3072 + segOff + h * 64 + dg * 8) = o;
}

// ---------------------------------------------------------------- LayerNorm (D=512), sums up to 3 inputs
__global__ __launch_bounds__(256) void ln_k(const float* __restrict__ in0,
                                            const float* __restrict__ in1,
                                            const float* __restrict__ in2,
                                            const float* __restrict__ g,
                                            const float* __restrict__ bb,
                                            float* __restrict__ outf,
                                            bf16_t* __restrict__ outb) {
    __shared__ float red[8];
    int row = blockIdx.x;
    int t = threadIdx.x;
    float x0 = in0[(size_t)row * 512 + t];
    float x1 = in0[(size_t)row * 512 + 256 + t];
    if (in1) {
        x0 += in1[(size_t)row * 512 + t];
        x1 += in1[(size_t)row * 512 + 256 + t];
    }
    if (in2) {
        x0 += in2[(size_t)row * 512 + t];
        x1 += in2[(size_t)row * 512 + 256 + t];
    }
    float s = x0 + x1, sq = x0 * x0 + x1 * x1;
#pragma unroll
    for (int d = 1; d < 64; d <<= 1) {
        s += __shfl_xor(s, d, 64);
        sq += __shfl_xor(sq, d, 64);
    }
    int w = t >> 6;
    if ((t & 63) == 0) { red[w] = s; red[4 + w] = sq; }
    __syncthreads();
    s = red[0] + red[1] + red[2] + red[3];
    sq = red[4] + red[5] + red[6] + red[7];
    float mean = s * (1.0f / 512.0f);
    float var = sq * (1.0f / 512.0f) - mean * mean;
    float rstd = rsqrtf(var + 1e-5f);
    float y0 = (x0 - mean) * rstd * g[t] + bb[t];
    float y1 = (x1 - mean) * rstd * g[256 + t] + bb[256 + t];
    if (outf) {
        outf[(size_t)row * 512 + t] = y0;
        outf[(size_t)row * 512 + 256 + t] = y1;
    }
    if (outb) {
        outb[(size_t)row * 512 + t] = (bf16_t)y0;
        outb[(size_t)row * 512 + 256 + t] = (bf16_t)y1;
    }
}

// ----------------------------------------------------------------
extern "C" void kernel_launch(void* const* d_in, const int* in_sizes, int n_in,
                              void* d_out, int out_size, void* d_ws, size_t ws_size,
                              hipStream_t stream) {
    (void)in_sizes; (void)n_in; (void)out_size; (void)ws_size;
    const float* x       = (const float*)d_in[0];
    const float* ref_mca = (const float*)d_in[1];
    const float* gate    = (const float*)d_in[2];
    const float *w[5], *wb[5], *ow[5], *ob[5];
    for (int p = 0; p < 5; ++p) {
        w[p]  = (const float*)d_in[3 + p * 4];
        wb[p] = (const float*)d_in[4 + p * 4];
        ow[p] = (const float*)d_in[5 + p * 4];
        ob[p] = (const float*)d_in[6 + p * 4];
    }
    const float* ln1_g = (const float*)d_in[23];
    const float* ln1_b = (const float*)d_in[24];
    const float* ln2_g = (const float*)d_in[25];
    const float* ln2_b = (const float*)d_in[26];
    const float* fc1_w = (const float*)d_in[27];
    const float* fc1_b = (const float*)d_in[28];
    const float* fc2_w = (const float*)d_in[29];
    const float* fc2_b = (const float*)d_in[30];

    char* ws = (char*)d_ws;
    size_t off = 0;
    auto alloc = [&](size_t bytes) {
        char* p = ws + off;
        off += (bytes + 255) & ~(size_t)255;
        return p;
    };
    bf16_t* xb    = (bf16_t*)alloc((size_t)4096 * 512 * 2);
    bf16_t* refb  = (bf16_t*)alloc((size_t)8192 * 512 * 2);
    bf16_t* Wxp   = (bf16_t*)alloc((size_t)5120 * 512 * 2);
    bf16_t* WRp   = (bf16_t*)alloc((size_t)2560 * 512 * 2);
    bf16_t* Wop   = (bf16_t*)alloc((size_t)512 * 3072 * 2);
    bf16_t* fc1p  = (bf16_t*)alloc((size_t)2048 * 512 * 2);
    bf16_t* fc2p  = (bf16_t*)alloc((size_t)512 * 2048 * 2);
    float*  bxp   = (float*)alloc((size_t)5120 * 4);
    float*  brp   = (float*)alloc((size_t)2560 * 4);
    float*  obc   = (float*)alloc((size_t)5 * 512 * 4);
    bf16_t* XP    = (bf16_t*)alloc((size_t)4096 * 5120 * 2);
    bf16_t* RP    = (bf16_t*)alloc((size_t)4096 * 2560 * 2);
    bf16_t* R0    = (bf16_t*)alloc((size_t)4096 * 1024 * 2);
    bf16_t* acat  = (bf16_t*)alloc((size_t)4096 * 3072 * 2);
    float*  newxA = (float*)alloc((size_t)4096 * 512 * 4);
    float*  newxB = (float*)alloc((size_t)4096 * 512 * 4);
    float*  ypA   = (float*)alloc((size_t)4096 * 512 * 4);
    float*  ypB   = (float*)alloc((size_t)4096 * 512 * 4);
    float*  hbuf  = (float*)alloc((size_t)4096 * 512 * 4);
    float*  Mpart = (float*)alloc((size_t)2 * 4 * 8 * 1024 * 4);
    float*  Lpart = (float*)alloc((size_t)2 * 4 * 8 * 1024 * 4);
    // aliases over dead-by-then regions:
    bf16_t* Opart = (bf16_t*)hbuf;  // 8.39MB; hbuf written only at LN1 (after attns)
    bf16_t* hb    = refb;           // refb dead after RP/R0 gemms
    bf16_t* ub    = XP;             // [4096,2048] bf16; XP dead after attns

    // ---- pack descriptors
    PackBDesc pb{};
    int nb = 0, blk = 0;
    auto addB = [&](const float* s, bf16_t* dptr, int chunks, int dstLd, int shift) {
        pb.src[nb] = s; pb.dst[nb] = dptr; pb.chunks[nb] = chunks;
        pb.dstLd[nb] = dstLd; pb.shift[nb] = shift;
        pb.blkOf[nb] = blk; blk += (chunks + 255) / 256; ++nb;
    };
    auto addLin = [&](const float* s, bf16_t* dptr, long elems) {
        addB(s, dptr, (int)(elems / 8), 0, 30);
    };
    addLin(x, xb, (long)4096 * 512);
    addLin(ref_mca, refb, (long)8192 * 512);
    addLin(w[0], Wxp, (long)512 * 512);                              // mca wq
    addLin(w[1], Wxp + (size_t)512 * 512, (long)512 * 512);          // ca wq
    addLin(w[2], Wxp + (size_t)1024 * 512, (long)1536 * 512);        // msa wqkv
    addLin(w[3], Wxp + (size_t)2560 * 512, (long)512 * 512);         // nsa wq
    addLin(w[3] + (size_t)1024 * 512, Wxp + (size_t)3072 * 512, (long)512 * 512);  // nsa wv
    addLin(w[4], Wxp + (size_t)3584 * 512, (long)1536 * 512);        // sa wqkv
    addLin(w[0] + (size_t)512 * 512, WRp, (long)1024 * 512);         // mca wk,wv
    addLin(w[1] + (size_t)512 * 512, WRp + (size_t)1024 * 512, (long)1024 * 512);  // ca wk,wv
    addLin(w[3] + (size_t)512 * 512, WRp + (size_t)2048 * 512, (long)512 * 512);   // nsa wk
    // o-weights: acat has 6 segments {mca_r0, mca_r1, ca, msa, nsa, sa} -> ow{0,0,1,2,3,4}
    const float* owSeg[6] = {ow[0], ow[0], ow[1], ow[2], ow[3], ow[4]};
    for (int s = 0; s < 6; ++s)
        addB(owSeg[s], Wop + (size_t)s * 512, 32768, 3072, 6);
    addLin(fc1_w, fc1p, (long)2048 * 512);
    addLin(fc2_w, fc2p, (long)512 * 2048);
    pb.nseg = nb; pb.blkOf[nb] = blk;
    packb_k<<<blk, 256, 0, stream>>>(pb);

    PackFDesc pf{};
    int nf = 0, fblk = 0;
    auto addF = [&](const float* s, float* dptr, int n) {
        pf.src[nf] = s; pf.dst[nf] = dptr; pf.n[nf] = n;
        pf.blkOf[nf] = fblk; fblk += (n + 255) / 256; ++nf;
    };
    addF(wb[0], bxp, 512);
    addF(wb[1], bxp + 512, 512);
    addF(wb[2], bxp + 1024, 1536);
    addF(wb[3], bxp + 2560, 512);
    addF(wb[3] + 1024, bxp + 3072, 512);
    addF(wb[4], bxp + 3584, 1536);
    addF(wb[0] + 512, brp, 1024);
    addF(wb[1] + 512, brp + 1024, 1024);
    addF(wb[3] + 512, brp + 2048, 512);
    for (int p = 0; p < 5; ++p) addF(ob[p], obc + p * 512, 512);
    pf.nseg = nf; pf.blkOf[nf] = fblk;
    packf_k<<<fblk, 256, 0, stream>>>(pf);

    // ---- projections (dbuf 2-phase GEMMs)
    gemm3<0, 128><<<dim3(40, 32), 256, 0, stream>>>(xb, 1024, 0, 512, Wxp, bxp, XP, 5120, nullptr, nullptr, 0, 512);
    gemm3<0, 128><<<dim3(20, 32), 256, 0, stream>>>(refb, 2048, 1024, 512, WRp, brp, RP, 2560, nullptr, nullptr, 0, 512);
    gemm3<0, 128><<<dim3(8, 32), 256, 0, stream>>>(refb, 2048, 0, 512, WRp, brp, R0, 1024, nullptr, nullptr, 0, 512);

    // ---- attentions (gated outputs into acat segments)
    // mca r0: banded direct
    attn3_k<1, 0><<<dim3(16, 8, 4), 256, 0, stream>>>(XP, 5120, R0, 1024, R0 + 512, 1024,
                                                      acat, 0, nullptr, nullptr, nullptr, gate, 0);
    // mca r1: banded direct
    attn3_k<1, 0><<<dim3(16, 8, 4), 256, 0, stream>>>(XP, 5120, RP, 2560, RP + 512, 2560,
                                                      acat, 512, nullptr, nullptr, nullptr, gate, 0);
    // ca: splitk
    attn3_k<0, 1><<<dim3(16, 8, 8), 256, 0, stream>>>(XP + 512, 5120, RP + 1024, 2560, RP + 1536, 2560,
                                                      nullptr, 0, Opart, Mpart, Lpart, gate, 1);
    merge_k<<<1024, 256, 0, stream>>>(Opart, Mpart, Lpart, acat, 1024);
    // msa: splitk fwd
    attn3_k<2, 1><<<dim3(16, 8, 8), 256, 0, stream>>>(XP + 1024, 5120, XP + 1536, 5120, XP + 2048, 5120,
                                                      nullptr, 0, Opart, Mpart, Lpart, gate, 2);
    merge_k<<<1024, 256, 0, stream>>>(Opart, Mpart, Lpart, acat, 1536);
    // nsa: splitk fwd (k from ref_last, v from x)
    attn3_k<2, 1><<<dim3(16, 8, 8), 256, 0, stream>>>(XP + 2560, 5120, RP + 2048, 2560, XP + 3072, 5120,
                                                      nullptr, 0, Opart, Mpart, Lpart, gate, 3);
    merge_k<<<1024, 256, 0, stream>>>(Opart, Mpart, Lpart, acat, 2048);
    // sa: splitk
    attn3_k<0, 1><<<dim3(16, 8, 8), 256, 0, stream>>>(XP + 3584, 5120, XP + 4096, 5120, XP + 4608, 5120,
                                                      nullptr, 0, Opart, Mpart, Lpart, gate, 4);
    merge_k<<<1024, 256, 0, stream>>>(Opart, Mpart, Lpart, acat, 2560);

    // ---- fused o-projection, split-K x2: newx = acat @ Wop^T (+ gate*ob mix on split 0)
    gemm3<4, 64><<<dim3(8, 32), 256, 0, stream>>>(acat, 1024, 0, 3072, Wop, nullptr, newxA, 512, gate, obc, 0, 1536);
    gemm3<4, 64><<<dim3(8, 32), 256, 0, stream>>>(acat, 1024, 0, 3072, Wop, nullptr, newxB, 512, nullptr, nullptr, 1536, 1536);

    // ---- LN1(newxA + newxB) -> h
    ln_k<<<4096, 256, 0, stream>>>(newxA, newxB, nullptr, ln1_g, ln1_b, hbuf, hb);
    // ---- G1: gelu(h @ fc1^T + b1) -> ub
    gemm3<1, 128><<<dim3(16, 32), 256, 0, stream>>>(hb, 1024, 0, 512, fc1p, fc1_b, ub, 2048, nullptr, nullptr, 0, 512);
    // ---- G2: ub @ fc2^T + b2 -> y, split-K x2
    gemm3<3, 64><<<dim3(8, 32), 256, 0, stream>>>(ub, 1024, 0, 2048, fc2p, fc2_b, ypA, 512, nullptr, nullptr, 0, 1024);
    gemm3<3, 64><<<dim3(8, 32), 256, 0, stream>>>(ub, 1024, 0, 2048, fc2p, nullptr, ypB, 512, nullptr, nullptr, 1024, 1024);
    // ---- LN2(h + yA + yB) -> out (f32)
    ln_k<<<4096, 256, 0, stream>>>(hbuf, ypA, ypB, ln2_g, ln2_b, (float*)d_out, nullptr);
}

// Round 7
// 315.555 us; speedup vs baseline: 1.3080x; 1.3080x over previous
//
#include <hip/hip_runtime.h>

typedef __bf16 bf16_t;
typedef bf16_t bf16x8 __attribute__((ext_vector_type(8)));
typedef float f32x4v __attribute__((ext_vector_type(4)));
typedef unsigned int u32;

__device__ __forceinline__ void gload16(const bf16_t* g, bf16_t* l) {
    __builtin_amdgcn_global_load_lds((const __attribute__((address_space(1))) u32*)g,
                                     (__attribute__((address_space(3))) u32*)l, 16, 0, 0);
}

// ---------------------------------------------------------------- pack f32 -> bf16 (segmented)
struct PackBDesc {
    int nseg;
    int blkOf[21];
    const float* src[20];
    bf16_t* dst[20];
    int chunks[20];
    int dstLd[20];
    int shift[20];
};

__global__ __launch_bounds__(256) void packb_k(PackBDesc d) {
    int b = blockIdx.x;
    int s = 0;
    while (s + 1 < d.nseg && b >= d.blkOf[s + 1]) ++s;
    int idx = (b - d.blkOf[s]) * 256 + threadIdx.x;
    if (idx >= d.chunks[s]) return;
    const float* src = d.src[s] + (size_t)idx * 8;
    int r = idx >> d.shift[s];
    int c8 = idx & ((1 << d.shift[s]) - 1);
    bf16_t* dst = d.dst[s] + (size_t)r * d.dstLd[s] + (size_t)c8 * 8;
    float4 v0 = reinterpret_cast<const float4*>(src)[0];
    float4 v1 = reinterpret_cast<const float4*>(src)[1];
    bf16x8 o;
    o[0] = (bf16_t)v0.x; o[1] = (bf16_t)v0.y; o[2] = (bf16_t)v0.z; o[3] = (bf16_t)v0.w;
    o[4] = (bf16_t)v1.x; o[5] = (bf16_t)v1.y; o[6] = (bf16_t)v1.z; o[7] = (bf16_t)v1.w;
    *reinterpret_cast<bf16x8*>(dst) = o;
}

// ---------------------------------------------------------------- pack f32 -> f32
struct PackFDesc {
    int nseg;
    int blkOf[15];
    const float* src[14];
    float* dst[14];
    int n[14];
};

__global__ __launch_bounds__(256) void packf_k(PackFDesc d) {
    int b = blockIdx.x;
    int s = 0;
    while (s + 1 < d.nseg && b >= d.blkOf[s + 1]) ++s;
    int idx = (b - d.blkOf[s]) * 256 + threadIdx.x;
    if (idx >= d.n[s]) return;
    d.dst[s][idx] = d.src[s][idx];
}

// ---------------------------------------------------------------- GEMM core (dbuf 2-phase)
// C = A @ B^T (+bias). A rows remapped (batch). EPI: 0 bf16, 1 gelu->bf16, 3 f32(+bias@bz0),
// 4 f32 (+ gate*obcat mix @bz0). Split-K via bz: kStart = bz*kLen, out += bz*outSplitStride.
template <int EPI, int BM, int BN>
__device__ __forceinline__ void gemm_core(
    int tm, int tn, int bz,
    const bf16_t* __restrict__ A, int aBS, int aRowOff, int lda,
    const bf16_t* __restrict__ B,
    const float* __restrict__ bias,
    void* __restrict__ Out, int ldo, size_t outSplitStride,
    const float* __restrict__ gate, const float* __restrict__ obcat,
    int kStart, int kLen) {
    constexpr int MB = BM / 32, NB = BN / 32, WM = BM / 2, WN = BN / 2;
    constexpr int CA = BM / 64, CB = BN / 64;
    __shared__ __attribute__((aligned(16))) bf16_t As[2][BM * 32];
    __shared__ __attribute__((aligned(16))) bf16_t Bs[2][BN * 32];
    const int tid = threadIdx.x, lane = tid & 63, w = tid >> 6;
    const int wm = w >> 1, wn = w & 1;
    const int l15 = lane & 15, l16 = lane >> 4;
    const int colS = (lane & 3) * 8, rowS = lane >> 2;

    auto remap = [&](int m) { return (m >> 10) * aBS + aRowOff + (m & 1023); };

    const bf16_t* aS[CA];
    const bf16_t* bS[CB];
#pragma unroll
    for (int c = 0; c < CA; ++c)
        aS[c] = A + (size_t)remap(tm * BM + (CA * w + c) * 16 + rowS) * lda + kStart + colS;
#pragma unroll
    for (int c = 0; c < CB; ++c)
        bS[c] = B + (size_t)(tn * BN + (CB * w + c) * 16 + rowS) * lda + kStart + colS;

    auto stage = [&](int buf, int t) {
        const size_t o = (size_t)t * 32;
#pragma unroll
        for (int c = 0; c < CA; ++c) gload16(aS[c] + o, &As[buf][(CA * w + c) * 512]);
#pragma unroll
        for (int c = 0; c < CB; ++c) gload16(bS[c] + o, &Bs[buf][(CB * w + c) * 512]);
    };

    f32x4v acc[MB][NB] = {};
    const int nt = kLen / 32;
    stage(0, 0);
    __syncthreads();
    int cur = 0;
    for (int t = 0; t < nt; ++t) {
        if (t + 1 < nt) stage(cur ^ 1, t + 1);
        bf16x8 af[MB], bff[NB];
#pragma unroll
        for (int mi = 0; mi < MB; ++mi)
            af[mi] = *reinterpret_cast<const bf16x8*>(&As[cur][(wm * WM + mi * 16 + l15) * 32 + l16 * 8]);
#pragma unroll
        for (int ni = 0; ni < NB; ++ni)
            bff[ni] = *reinterpret_cast<const bf16x8*>(&Bs[cur][(wn * WN + ni * 16 + l15) * 32 + l16 * 8]);
#pragma unroll
        for (int mi = 0; mi < MB; ++mi)
#pragma unroll
            for (int ni = 0; ni < NB; ++ni)
                acc[mi][ni] = __builtin_amdgcn_mfma_f32_16x16x32_bf16(af[mi], bff[ni], acc[mi][ni], 0, 0, 0);
        __syncthreads();
        cur ^= 1;
    }

#pragma unroll
    for (int mi = 0; mi < MB; ++mi) {
#pragma unroll
        for (int ni = 0; ni < NB; ++ni) {
#pragma unroll
            for (int i = 0; i < 4; ++i) {
                int row = tm * BM + wm * WM + mi * 16 + l16 * 4 + i;
                int n = tn * BN + wn * WN + ni * 16 + l15;
                float v = acc[mi][ni][i];
                if (bias && bz == 0) v += bias[n];
                if constexpr (EPI == 0) {
                    ((bf16_t*)Out)[(size_t)row * ldo + n] = (bf16_t)v;
                } else if constexpr (EPI == 1) {
                    float g = 0.5f * v * (1.0f + erff(v * 0.70710678118654752f));
                    ((bf16_t*)Out)[(size_t)row * ldo + n] = (bf16_t)g;
                } else if constexpr (EPI == 3) {
                    ((float*)Out + (size_t)bz * outSplitStride)[(size_t)row * ldo + n] = v;
                } else {
                    if (obcat && bz == 0) {
#pragma unroll
                        for (int p = 0; p < 5; ++p) {
                            float c = (p == 0) ? 2.0f : 1.0f;  // mca's ob appears twice
                            v += gate[row * 5 + p] * c * obcat[p * 512 + n];
                        }
                    }
                    ((float*)Out + (size_t)bz * outSplitStride)[(size_t)row * ldo + n] = v;
                }
            }
        }
    }
}

// ---------------------------------------------------------------- batched projection GEMM
struct ProjDesc {
    const bf16_t* A[3];
    int aBS[3], aRowOff[3];
    const bf16_t* B[3];
    const float* bias[3];
    bf16_t* Out[3];
    int ldo[3];
    int ntn[3], base[3];
};

__global__ __launch_bounds__(256) void proj_k(ProjDesc d) {
    int bx = blockIdx.x;
    int s = (bx >= d.base[2]) ? 2 : (bx >= d.base[1]) ? 1 : 0;
    int local = bx - d.base[s];
    int tn = local % d.ntn[s];
    int tm = local / d.ntn[s];
    gemm_core<0, 128, 64>(tm, tn, 0, d.A[s], d.aBS[s], d.aRowOff[s], 512,
                          d.B[s], d.bias[s], d.Out[s], d.ldo[s], 0, nullptr, nullptr, 0, 512);
}

// ---------------------------------------------------------------- standalone GEMM
template <int EPI, int BM, int BN>
__global__ __launch_bounds__(256) void gemmT(
    const bf16_t* __restrict__ A, int aBS, int aRowOff, int lda,
    const bf16_t* __restrict__ B, const float* __restrict__ bias,
    void* __restrict__ Out, int ldo, size_t outSplitStride,
    const float* __restrict__ gate, const float* __restrict__ obcat, int kPerSplit) {
    gemm_core<EPI, BM, BN>(blockIdx.y, blockIdx.x, blockIdx.z, A, aBS, aRowOff, lda, B, bias,
                           Out, ldo, outSplitStride, gate, obcat, blockIdx.z * kPerSplit, kPerSplit);
}

// ---------------------------------------------------------------- batched attention (6 units)
// units 0,1: banded (mask=1) direct gated write; units 2..5: splitk x2 gated partials.
struct AttnDesc {
    const bf16_t* Q[6];
    const bf16_t* K[6];
    const bf16_t* V[6];
    int ldq[6], ldk[6], ldv[6];
    int segOff[6], gidx[6], mask[6];
    bf16_t* acat;
    bf16_t* Op;   // 4 units x 65536 rows x 64
    float* Mp;    // 4 units x 65536
    float* Lp;
    const float* gate;
};

__global__ __launch_bounds__(256) void attn4_k(AttnDesc d) {
    __shared__ __attribute__((aligned(16))) bf16_t Ks[32][72];
    __shared__ __attribute__((aligned(16))) bf16_t Vt[64][40];
    __shared__ __attribute__((aligned(16))) bf16_t Ps[4][16][40];

    int bx = blockIdx.x;
    int u, local;
    if (bx < 512) { u = 0; local = bx; }
    else if (bx < 1024) { u = 1; local = bx - 512; }
    else if (bx < 2048) { u = 2; local = bx - 1024; }
    else if (bx < 3072) { u = 3; local = bx - 2048; }
    else if (bx < 4096) { u = 4; local = bx - 3072; }
    else { u = 5; local = bx - 4096; }
    const bool splitk = (u >= 2);
    const int mask = d.mask[u];
    const int qt = local & 15, h = (local >> 4) & 7, z = local >> 7;

    const int tid = threadIdx.x;
    const int lane = tid & 63;
    const int w = tid >> 6;
    const int l15 = lane & 15, l16 = lane >> 4;

    int b, split;
    if (splitk) { b = z & 3; split = z >> 2; } else { b = z; split = 0; }

    const int qr = qt * 64 + w * 16;
    const int qrow = b * 1024 + qr;
    const int qblk = qr >> 5;
    const int qg = ((w & 1) * 16) + l15;

    const bf16_t* Q = d.Q[u];
    const int ldq = d.ldq[u], ldk = d.ldk[u], ldv = d.ldv[u];

    bf16x8 aq[2];
#pragma unroll
    for (int s = 0; s < 2; ++s)
        aq[s] = *reinterpret_cast<const bf16x8*>(
            Q + (size_t)(qrow + l15) * ldq + h * 64 + s * 32 + l16 * 8);

    float mrow = -1e30f, lsum = 0.f;
    f32x4v accO[4] = {};

    const int srow = tid >> 3, scol8 = (tid & 7) * 8;
    const bf16_t* kbase = d.K[u] + (size_t)(b * 1024) * ldk + h * 64 + scol8;
    const bf16_t* vbase = d.V[u] + (size_t)(b * 1024) * ldv + h * 64 + scol8;

    int kt0, ktEnd;
    if (splitk) { kt0 = split * 16; ktEnd = kt0 + 16; }
    else {
        int qb0 = qt * 2;
        kt0 = qb0 - 3; if (kt0 < 0) kt0 = 0;
        ktEnd = qb0 + 5; if (ktEnd > 32) ktEnd = 32;
    }

    bf16x8 rk, rv, rk2, rv2;
    rk = *reinterpret_cast<const bf16x8*>(kbase + (size_t)(kt0 * 32 + srow) * ldk);
    rv = *reinterpret_cast<const bf16x8*>(vbase + (size_t)(kt0 * 32 + srow) * ldv);

    for (int kt = kt0; kt < ktEnd; ++kt) {
        __syncthreads();
        *reinterpret_cast<bf16x8*>(&Ks[srow][scol8]) = rk;
#pragma unroll
        for (int j = 0; j < 8; ++j) {
            int dd = scol8 + j;
            Vt[dd][srow ^ (((dd >> 3) & 3) << 3)] = rv[j];
        }
        if (kt + 1 < ktEnd) {
            rk2 = *reinterpret_cast<const bf16x8*>(kbase + (size_t)((kt + 1) * 32 + srow) * ldk);
            rv2 = *reinterpret_cast<const bf16x8*>(vbase + (size_t)((kt + 1) * 32 + srow) * ldv);
        }
        __syncthreads();

        int bd = qblk - kt; if (bd < 0) bd = -bd;
        const bool active = (mask != 1) || (bd <= 3);
        if (active) {
            bf16x8 k00 = *reinterpret_cast<const bf16x8*>(&Ks[l15][l16 * 8]);
            bf16x8 k01 = *reinterpret_cast<const bf16x8*>(&Ks[l15][32 + l16 * 8]);
            bf16x8 k10 = *reinterpret_cast<const bf16x8*>(&Ks[16 + l15][l16 * 8]);
            bf16x8 k11 = *reinterpret_cast<const bf16x8*>(&Ks[16 + l15][32 + l16 * 8]);
            f32x4v z0 = {}, z1 = {};
            z0 = __builtin_amdgcn_mfma_f32_16x16x32_bf16(k00, aq[0], z0, 0, 0, 0);
            z0 = __builtin_amdgcn_mfma_f32_16x16x32_bf16(k01, aq[1], z0, 0, 0, 0);
            z1 = __builtin_amdgcn_mfma_f32_16x16x32_bf16(k10, aq[0], z1, 0, 0, 0);
            z1 = __builtin_amdgcn_mfma_f32_16x16x32_bf16(k11, aq[1], z1, 0, 0, 0);

            const bool needMask = (mask == 1) || (mask == 2 && bd <= 3);
            float p[2][4];
#pragma unroll
            for (int n = 0; n < 2; ++n) {
                f32x4v sv = n ? z1 : z0;
#pragma unroll
                for (int i = 0; i < 4; ++i) {
                    float v = sv[i] * 0.125f;
                    if (needMask) {
                        int k5 = n * 16 + l16 * 4 + i;
                        int dq = qg - k5; if (dq < 0) dq = -dq;
                        bool inside = (dq <= 3);
                        if (mask == 1 ? !inside : inside) v = -1e30f;
                    }
                    p[n][i] = v;
                }
            }
            float tmx = p[0][0];
            tmx = fmaxf(tmx, p[0][1]); tmx = fmaxf(tmx, p[0][2]); tmx = fmaxf(tmx, p[0][3]);
            tmx = fmaxf(tmx, p[1][0]); tmx = fmaxf(tmx, p[1][1]);
            tmx = fmaxf(tmx, p[1][2]); tmx = fmaxf(tmx, p[1][3]);
            tmx = fmaxf(tmx, __shfl_xor(tmx, 16, 64));
            tmx = fmaxf(tmx, __shfl_xor(tmx, 32, 64));
            float mn = fmaxf(mrow, tmx);
            float fac = __expf(mrow - mn);
            mrow = mn;
            float rs = 0.f;
#pragma unroll
            for (int n = 0; n < 2; ++n)
#pragma unroll
                for (int i = 0; i < 4; ++i) {
                    p[n][i] = __expf(p[n][i] - mn);
                    rs += p[n][i];
                }
            rs += __shfl_xor(rs, 16, 64);
            rs += __shfl_xor(rs, 32, 64);
            lsum = lsum * fac + rs;

            float facq[4];
#pragma unroll
            for (int i = 0; i < 4; ++i) facq[i] = __shfl(fac, l16 * 4 + i, 64);
#pragma unroll
            for (int dblk = 0; dblk < 4; ++dblk)
#pragma unroll
                for (int i = 0; i < 4; ++i) accO[dblk][i] *= facq[i];

#pragma unroll
            for (int n = 0; n < 2; ++n)
#pragma unroll
                for (int i = 0; i < 4; ++i)
                    Ps[w][l15][n * 16 + l16 * 4 + i] = (bf16_t)p[n][i];
            bf16x8 pa = *reinterpret_cast<const bf16x8*>(&Ps[w][l15][l16 * 8]);

#pragma unroll
            for (int dblk = 0; dblk < 4; ++dblk) {
                int dd = dblk * 16 + l15;
                bf16x8 bv = *reinterpret_cast<const bf16x8*>(&Vt[dd][(l16 ^ ((dd >> 3) & 3)) * 8]);
                accO[dblk] = __builtin_amdgcn_mfma_f32_16x16x32_bf16(pa, bv, accO[dblk], 0, 0, 0);
            }
        }
        rk = rk2; rv = rv2;
    }

    if (!splitk) {
        float inv = 1.0f / lsum;
        float invq[4];
#pragma unroll
        for (int i = 0; i < 4; ++i) invq[i] = __shfl(inv, l16 * 4 + i, 64);
#pragma unroll
        for (int dblk = 0; dblk < 4; ++dblk)
#pragma unroll
            for (int i = 0; i < 4; ++i) {
                float g = d.gate[(size_t)(qrow + l16 * 4 + i) * 5 + d.gidx[u]];
                d.acat[(size_t)(qrow + l16 * 4 + i) * 3072 + d.segOff[u] + h * 64 + dblk * 16 + l15] =
                    (bf16_t)(accO[dblk][i] * invq[i] * g);
            }
    } else {
        const int su = u - 2;
        bf16_t* Opu = d.Op + (size_t)su * 65536 * 64;
        float* Mpu = d.Mp + su * 65536;
        float* Lpu = d.Lp + su * 65536;
        int pb = ((split * 4 + b) * 8 + h) * 1024 + qr;
        if (l16 == 0) { Mpu[pb + l15] = mrow; Lpu[pb + l15] = lsum; }
#pragma unroll
        for (int dblk = 0; dblk < 4; ++dblk)
#pragma unroll
            for (int i = 0; i < 4; ++i) {
                float g = d.gate[(size_t)(qrow + l16 * 4 + i) * 5 + d.gidx[u]];
                Opu[(size_t)(pb + l16 * 4 + i) * 64 + dblk * 16 + l15] = (bf16_t)(accO[dblk][i] * g);
            }
    }
}

// ---------------------------------------------------------------- batched split-K merge (4 units)
struct MergeDesc {
    const bf16_t* Op;
    const float* Mp;
    const float* Lp;
    bf16_t* acat;
    int segOff[4];
};

__global__ __launch_bounds__(256) void merge4_k(MergeDesc d) {
    int u = blockIdx.x >> 10;
    int idx = (blockIdx.x & 1023) * 256 + threadIdx.x;
    const bf16_t* Opu = d.Op + (size_t)u * 65536 * 64;
    const float* Mpu = d.Mp + u * 65536;
    const float* Lpu = d.Lp + u * 65536;
    int dg = idx & 7;
    int q = (idx >> 3) & 1023;
    int h = (idx >> 13) & 7;
    int b = idx >> 16;
    int r0 = ((0 * 4 + b) * 8 + h) * 1024 + q;
    int r1 = ((1 * 4 + b) * 8 + h) * 1024 + q;
    float m0 = Mpu[r0], m1 = Mpu[r1], l0 = Lpu[r0], l1 = Lpu[r1];
    float M = fmaxf(m0, m1);
    float w0 = __expf(m0 - M), w1 = __expf(m1 - M);
    float den = 1.0f / (l0 * w0 + l1 * w1);
    bf16x8 o0 = *reinterpret_cast<const bf16x8*>(Opu + (size_t)r0 * 64 + dg * 8);
    bf16x8 o1 = *reinterpret_cast<const bf16x8*>(Opu + (size_t)r1 * 64 + dg * 8);
    bf16x8 o;
#pragma unroll
    for (int j = 0; j < 8; ++j)
        o[j] = (bf16_t)(((float)o0[j] * w0 + (float)o1[j] * w1) * den);
    *reinterpret_cast<bf16x8*>(d.acat + (size_t)(b * 1024 + q) * 3072 + d.segOff[u] + h * 64 + dg * 8) = o;
}

// ---------------------------------------------------------------- LayerNorm (D=512), sums up to 3
__global__ __launch_bounds__(256) void ln_k(const float* __restrict__ in0,
                                            const float* __restrict__ in1,
                                            const float* __restrict__ in2,
                                            const float* __restrict__ g,
                                            const float* __restrict__ bb,
                                            float* __restrict__ outf,
                                            bf16_t* __restrict__ outb) {
    __shared__ float red[8];
    int row = blockIdx.x;
    int t = threadIdx.x;
    float x0 = in0[(size_t)row * 512 + t];
    float x1 = in0[(size_t)row * 512 + 256 + t];
    if (in1) {
        x0 += in1[(size_t)row * 512 + t];
        x1 += in1[(size_t)row * 512 + 256 + t];
    }
    if (in2) {
        x0 += in2[(size_t)row * 512 + t];
        x1 += in2[(size_t)row * 512 + 256 + t];
    }
    float s = x0 + x1, sq = x0 * x0 + x1 * x1;
#pragma unroll
    for (int d = 1; d < 64; d <<= 1) {
        s += __shfl_xor(s, d, 64);
        sq += __shfl_xor(sq, d, 64);
    }
    int w = t >> 6;
    if ((t & 63) == 0) { red[w] = s; red[4 + w] = sq; }
    __syncthreads();
    s = red[0] + red[1] + red[2] + red[3];
    sq = red[4] + red[5] + red[6] + red[7];
    float mean = s * (1.0f / 512.0f);
    float var = sq * (1.0f / 512.0f) - mean * mean;
    float rstd = rsqrtf(var + 1e-5f);
    float y0 = (x0 - mean) * rstd * g[t] + bb[t];
    float y1 = (x1 - mean) * rstd * g[256 + t] + bb[256 + t];
    if (outf) {
        outf[(size_t)row * 512 + t] = y0;
        outf[(size_t)row * 512 + 256 + t] = y1;
    }
    if (outb) {
        outb[(size_t)row * 512 + t] = (bf16_t)y0;
        outb[(size_t)row * 512 + 256 + t] = (bf16_t)y1;
    }
}

// ----------------------------------------------------------------
extern "C" void kernel_launch(void* const* d_in, const int* in_sizes, int n_in,
                              void* d_out, int out_size, void* d_ws, size_t ws_size,
                              hipStream_t stream) {
    (void)in_sizes; (void)n_in; (void)out_size; (void)ws_size;
    const float* x       = (const float*)d_in[0];
    const float* ref_mca = (const float*)d_in[1];
    const float* gate    = (const float*)d_in[2];
    const float *w[5], *wb[5], *ow[5], *ob[5];
    for (int p = 0; p < 5; ++p) {
        w[p]  = (const float*)d_in[3 + p * 4];
        wb[p] = (const float*)d_in[4 + p * 4];
        ow[p] = (const float*)d_in[5 + p * 4];
        ob[p] = (const float*)d_in[6 + p * 4];
    }
    const float* ln1_g = (const float*)d_in[23];
    const float* ln1_b = (const float*)d_in[24];
    const float* ln2_g = (const float*)d_in[25];
    const float* ln2_b = (const float*)d_in[26];
    const float* fc1_w = (const float*)d_in[27];
    const float* fc1_b = (const float*)d_in[28];
    const float* fc2_w = (const float*)d_in[29];
    const float* fc2_b = (const float*)d_in[30];

    char* ws = (char*)d_ws;
    size_t off = 0;
    auto alloc = [&](size_t bytes) {
        char* p = ws + off;
        off += (bytes + 255) & ~(size_t)255;
        return p;
    };
    const size_t S2 = (size_t)4096 * 512;
    bf16_t* xb    = (bf16_t*)alloc(S2 * 2);
    bf16_t* refb  = (bf16_t*)alloc((size_t)8192 * 512 * 2);
    bf16_t* Wxp   = (bf16_t*)alloc((size_t)5120 * 512 * 2);
    bf16_t* WRp   = (bf16_t*)alloc((size_t)2560 * 512 * 2);
    bf16_t* Wop   = (bf16_t*)alloc((size_t)512 * 3072 * 2);
    bf16_t* fc1p  = (bf16_t*)alloc((size_t)2048 * 512 * 2);
    bf16_t* fc2p  = (bf16_t*)alloc((size_t)512 * 2048 * 2);
    float*  bxp   = (float*)alloc((size_t)5120 * 4);
    float*  brp   = (float*)alloc((size_t)2560 * 4);
    float*  obc   = (float*)alloc((size_t)5 * 512 * 4);
    bf16_t* XP    = (bf16_t*)alloc((size_t)4096 * 5120 * 2);
    bf16_t* RP    = (bf16_t*)alloc((size_t)4096 * 2560 * 2);
    bf16_t* R0    = (bf16_t*)alloc((size_t)4096 * 1024 * 2);
    bf16_t* acat  = (bf16_t*)alloc((size_t)4096 * 3072 * 2);
    float*  newx  = (float*)alloc(S2 * 4 * 2);      // 2 split halves
    float*  hbuf  = (float*)alloc(S2 * 4);
    bf16_t* Opart = (bf16_t*)alloc((size_t)4 * 65536 * 64 * 2);
    float*  Mpart = (float*)alloc((size_t)4 * 65536 * 4);
    float*  Lpart = (float*)alloc((size_t)4 * 65536 * 4);
    // aliases over dead-by-then regions:
    bf16_t* hb  = refb;      // refb dead after proj_k
    bf16_t* ub  = XP;        // XP dead after attn4_k
    float*  yp  = newx;      // newx consumed by LN1 before G2 writes (2 halves)

    // ---- pack descriptors
    PackBDesc pb{};
    int nb = 0, blk = 0;
    auto addB = [&](const float* s, bf16_t* dptr, int chunks, int dstLd, int shift) {
        pb.src[nb] = s; pb.dst[nb] = dptr; pb.chunks[nb] = chunks;
        pb.dstLd[nb] = dstLd; pb.shift[nb] = shift;
        pb.blkOf[nb] = blk; blk += (chunks + 255) / 256; ++nb;
    };
    auto addLin = [&](const float* s, bf16_t* dptr, long elems) {
        addB(s, dptr, (int)(elems / 8), 0, 30);
    };
    addLin(x, xb, (long)4096 * 512);
    addLin(ref_mca, refb, (long)8192 * 512);
    addLin(w[0], Wxp, (long)512 * 512);                                            // mca wq
    addLin(w[1], Wxp + (size_t)512 * 512, (long)512 * 512);                        // ca wq
    addLin(w[2], Wxp + (size_t)1024 * 512, (long)1536 * 512);                      // msa wqkv
    addLin(w[3], Wxp + (size_t)2560 * 512, (long)512 * 512);                       // nsa wq
    addLin(w[3] + (size_t)1024 * 512, Wxp + (size_t)3072 * 512, (long)512 * 512);  // nsa wv
    addLin(w[4], Wxp + (size_t)3584 * 512, (long)1536 * 512);                      // sa wqkv
    addLin(w[0] + (size_t)512 * 512, WRp, (long)1024 * 512);                       // mca wk,wv
    addLin(w[1] + (size_t)512 * 512, WRp + (size_t)1024 * 512, (long)1024 * 512);  // ca wk,wv
    addLin(w[3] + (size_t)512 * 512, WRp + (size_t)2048 * 512, (long)512 * 512);   // nsa wk
    // o-weights: acat segments {mca_r0, mca_r1, ca, msa, nsa, sa} -> ow{0,0,1,2,3,4}
    const float* owSeg[6] = {ow[0], ow[0], ow[1], ow[2], ow[3], ow[4]};
    for (int s = 0; s < 6; ++s)
        addB(owSeg[s], Wop + (size_t)s * 512, 32768, 3072, 6);
    addLin(fc1_w, fc1p, (long)2048 * 512);
    addLin(fc2_w, fc2p, (long)512 * 2048);
    pb.nseg = nb; pb.blkOf[nb] = blk;
    packb_k<<<blk, 256, 0, stream>>>(pb);

    PackFDesc pf{};
    int nf = 0, fblk = 0;
    auto addF = [&](const float* s, float* dptr, int n) {
        pf.src[nf] = s; pf.dst[nf] = dptr; pf.n[nf] = n;
        pf.blkOf[nf] = fblk; fblk += (n + 255) / 256; ++nf;
    };
    addF(wb[0], bxp, 512);
    addF(wb[1], bxp + 512, 512);
    addF(wb[2], bxp + 1024, 1536);
    addF(wb[3], bxp + 2560, 512);
    addF(wb[3] + 1024, bxp + 3072, 512);
    addF(wb[4], bxp + 3584, 1536);
    addF(wb[0] + 512, brp, 1024);
    addF(wb[1] + 512, brp + 1024, 1024);
    addF(wb[3] + 512, brp + 2048, 512);
    for (int p = 0; p < 5; ++p) addF(ob[p], obc + p * 512, 512);
    pf.nseg = nf; pf.blkOf[nf] = fblk;
    packf_k<<<fblk, 256, 0, stream>>>(pf);

    // ---- batched projections: XP(N=5120), RP(N=2560), R0(N=1024); BM=128 BN=64
    ProjDesc pd{};
    pd.A[0] = xb;   pd.aBS[0] = 1024; pd.aRowOff[0] = 0;    pd.B[0] = Wxp; pd.bias[0] = bxp; pd.Out[0] = XP; pd.ldo[0] = 5120; pd.ntn[0] = 80;
    pd.A[1] = refb; pd.aBS[1] = 2048; pd.aRowOff[1] = 1024; pd.B[1] = WRp; pd.bias[1] = brp; pd.Out[1] = RP; pd.ldo[1] = 2560; pd.ntn[1] = 40;
    pd.A[2] = refb; pd.aBS[2] = 2048; pd.aRowOff[2] = 0;    pd.B[2] = WRp; pd.bias[2] = brp; pd.Out[2] = R0; pd.ldo[2] = 1024; pd.ntn[2] = 16;
    pd.base[0] = 0; pd.base[1] = 80 * 32; pd.base[2] = 80 * 32 + 40 * 32;
    proj_k<<<80 * 32 + 40 * 32 + 16 * 32, 256, 0, stream>>>(pd);

    // ---- batched attention (6 units, 5120 blocks)
    AttnDesc ad{};
    auto setU = [&](int u, const bf16_t* Q, int lq, const bf16_t* K, int lk,
                    const bf16_t* V, int lv, int seg, int gi, int mk) {
        ad.Q[u] = Q; ad.ldq[u] = lq; ad.K[u] = K; ad.ldk[u] = lk; ad.V[u] = V; ad.ldv[u] = lv;
        ad.segOff[u] = seg; ad.gidx[u] = gi; ad.mask[u] = mk;
    };
    setU(0, XP, 5120, R0, 1024, R0 + 512, 1024, 0, 0, 1);
    setU(1, XP, 5120, RP, 2560, RP + 512, 2560, 512, 0, 1);
    setU(2, XP + 512, 5120, RP + 1024, 2560, RP + 1536, 2560, 1024, 1, 0);
    setU(3, XP + 1024, 5120, XP + 1536, 5120, XP + 2048, 5120, 1536, 2, 2);
    setU(4, XP + 2560, 5120, RP + 2048, 2560, XP + 3072, 5120, 2048, 3, 2);
    setU(5, XP + 3584, 5120, XP + 4096, 5120, XP + 4608, 5120, 2560, 4, 0);
    ad.acat = acat; ad.Op = Opart; ad.Mp = Mpart; ad.Lp = Lpart; ad.gate = gate;
    attn4_k<<<5120, 256, 0, stream>>>(ad);

    // ---- batched merge (4 splitk units)
    MergeDesc md{};
    md.Op = Opart; md.Mp = Mpart; md.Lp = Lpart; md.acat = acat;
    md.segOff[0] = 1024; md.segOff[1] = 1536; md.segOff[2] = 2048; md.segOff[3] = 2560;
    merge4_k<<<4096, 256, 0, stream>>>(md);

    // ---- fused o-projection, split-K x2 in ONE dispatch: newx halves = acat @ Wop^T
    gemmT<4, 64, 64><<<dim3(8, 64, 2), 256, 0, stream>>>(acat, 1024, 0, 3072, Wop, nullptr,
                                                         newx, 512, S2, gate, obc, 1536);
    // ---- LN1(newxA + newxB) -> h
    ln_k<<<4096, 256, 0, stream>>>(newx, newx + S2, nullptr, ln1_g, ln1_b, hbuf, hb);
    // ---- G1: gelu(h @ fc1^T + b1) -> ub
    gemmT<1, 64, 128><<<dim3(16, 64, 1), 256, 0, stream>>>(hb, 1024, 0, 512, fc1p, fc1_b,
                                                           ub, 2048, 0, nullptr, nullptr, 512);
    // ---- G2: ub @ fc2^T + b2 -> y halves, split-K x2 in ONE dispatch
    gemmT<3, 64, 64><<<dim3(8, 64, 2), 256, 0, stream>>>(ub, 1024, 0, 2048, fc2p, fc2_b,
                                                         yp, 512, S2, nullptr, nullptr, 1024);
    // ---- LN2(h + yA + yB) -> out (f32)
    ln_k<<<4096, 256, 0, stream>>>(hbuf, yp, yp + S2, ln2_g, ln2_b, (float*)d_out, nullptr);
}